// Round 10
// baseline (102126.062 us; speedup 1.0000x reference)
//
#include <hip/hip_runtime.h>
#include <cstdint>
#include <cstddef>

#define NWG 64
#define NTHR 640  // 10 waves: 0-1 pollers, 2-9 compute
#define UPW 16    // hidden units per WG
#define TSTEPS 16384
#define HDIM 1024
#define EDIM 13
#define HLDIM 512

typedef unsigned long long ull;

// ---------------------------------------------------------------------------
// Init kernel: re-arm the tagged h-record ring and u-record every call (d_ws
// is poisoned once with 0xAA and never re-poisoned between graph replays; a
// finished replay also leaves end-state tags behind, so every tag word must
// be rewritten each launch).
// hrec[parity][i] = { low32: f32 h value, high32: u32 step tag }, 4 parities.
// ---------------------------------------------------------------------------
__global__ void k_init(const float* __restrict__ h0, ull* __restrict__ hrec,
                       ull* __restrict__ urec) {
  int i = threadIdx.x;  // 1024 threads
  hrec[i] = (ull)__float_as_uint(h0[i]);  // {h0, tag=0}
  hrec[HDIM + i] = 0ull;
  hrec[2 * HDIM + i] = 0ull;
  hrec[3 * HDIM + i] = 0ull;
  if (i < HLDIM) urec[i] = 0ull;
}

// ---------------------------------------------------------------------------
// Persistent LSTM kernel with PRODUCER/CONSUMER WAVE SPECIALIZATION.
// R9 post-mortem: probe contention largely falsified (8x fewer pollers, same
// wall). Residual model: the step wall is a serial chain publish(0.3us) ->
// detect(0.7-1us, poll starts only after the barrier) -> compute(0.4us).
// Fix: dedicate waves 0-1 as pollers. Poller p handles steps t%2==p^1; it
// continuously probes the next step's records WHILE compute waves (2-9) work
// on the current step, so detection overlaps compute+publish. Handoff via a
// 4-deep LDS h parity ring + LDS rdy flags (CU-local spin, ~100cyc). No
// __syncthreads in the step loop. Compute waves never touch the coherent
// path.
// W residency: units 0..7 in 128 KB LDS, units 8..15 streamed from L2
// (1 MB/XCD working set, L2-resident). Cross-WG transport: self-validating
// {value, tag} 8-byte records, 4-deep global parity ring, relaxed
// agent-scope atomics (single-copy, serviced at the device coherent point ->
// immune to non-coherent per-XCD L2s).
// LDS parity-p overwrite safety: a poller rewrites parity p only after ALL
// tag-(t+3) records exist, which includes our own WG's units, which requires
// our compute waves to have finished step t+3 -> long done reading parity p
// (last read at step t). Poller drains lgkmcnt before the flag write; LDS
// in-order service makes flag visibility imply data visibility.
// ---------------------------------------------------------------------------
__global__ __launch_bounds__(NTHR) void k_main(
    const float* __restrict__ x, const float* __restrict__ c0,
    const float* __restrict__ Wih, const float* __restrict__ Whh,
    const float* __restrict__ bih, const float* __restrict__ bhh,
    const float* __restrict__ W1, const float* __restrict__ b1,
    const float* __restrict__ W2, const float* __restrict__ b2,
    float* __restrict__ out, ull* hrec, ull* urec) {
  const int w = blockIdx.x;
  const int tid = threadIdx.x;
  const int wave = tid >> 6;  // 0..9
  const int lane = tid & 63;
  const int hi = lane >> 5;  // 0/1: which unit of a compute wave
  const int sl = lane & 31;  // sub-lane within the half
  const int cwave = wave - 2;
  const int lu = (cwave >= 0) ? 2 * cwave + hi : 0;  // local unit 0..15

  __shared__ float4 lds_w4[32 * 256];  // units 0..7: row r=4*lu+g, 128 KB
  __shared__ float4 lds_h4[4 * 256];   // 4-deep parity ring of h
  __shared__ float lds_wih[64][17];    // row = 4*lu+g, stride 17
  __shared__ float lds_bsum[64];
  __shared__ float lds_xbuf[4][16];
  __shared__ float lds_r0[8], lds_r1[8];
  __shared__ int lds_rdy[4];
  float* lds_hf = (float*)lds_h4;  // [4][1024] flat

  // ---- stage W for units 0..7 into LDS (one-time, coalesced) -------------
#pragma unroll
  for (int it = 0; it < 13; ++it) {
    int idx = it * NTHR + tid;  // 0..8191 float4s
    if (idx < 8192) {
      int r = idx >> 8;  // LDS row 0..31 (r = 4*lu + g)
      int c4 = idx & 255;
      int lu_ = r >> 2, g_ = r & 3;
      int grow = g_ * HDIM + UPW * w + lu_;
      lds_w4[r * 256 + c4] = ((const float4*)(Whh + (size_t)grow * HDIM))[c4];
    }
  }
  if (tid < 64) {
    int lu_ = tid >> 2, g_ = tid & 3;
    int grow = g_ * HDIM + UPW * w + lu_;
#pragma unroll
    for (int e = 0; e < EDIM; ++e) lds_wih[tid][e] = Wih[grow * EDIM + e];
    lds_bsum[tid] = bih[grow] + bhh[grow];
  }
  if (tid < 4) lds_rdy[tid] = -1;
  // cell state: lane sl==0 of each compute half owns unit 16w+lu
  float cst = (cwave >= 0) ? c0[UPW * w + lu] : 0.f;
  __syncthreads();

  if (wave < 2) {
    // =========================== POLLER WAVES ============================
    for (int t = 1 + wave; t <= TSTEPS; t += 2) {
      const int p = (t - 1) & 3;
      // x_t prefetch, issued before the probe loop
      float xv = 0.f;
      if (lane < EDIM) xv = x[(size_t)(t - 1) * EDIM + lane];

      const ull* src = hrec + (size_t)p * HDIM + lane;
      const unsigned want = (unsigned)(t - 1);
      ull v0, v1, v2, v3, v4, v5, v6, v7, v8, v9, va, vb, vc, vd, ve, vf;
      for (;;) {
        v0 = __hip_atomic_load(&src[0], __ATOMIC_RELAXED,
                               __HIP_MEMORY_SCOPE_AGENT);
        v1 = __hip_atomic_load(&src[64], __ATOMIC_RELAXED,
                               __HIP_MEMORY_SCOPE_AGENT);
        v2 = __hip_atomic_load(&src[128], __ATOMIC_RELAXED,
                               __HIP_MEMORY_SCOPE_AGENT);
        v3 = __hip_atomic_load(&src[192], __ATOMIC_RELAXED,
                               __HIP_MEMORY_SCOPE_AGENT);
        v4 = __hip_atomic_load(&src[256], __ATOMIC_RELAXED,
                               __HIP_MEMORY_SCOPE_AGENT);
        v5 = __hip_atomic_load(&src[320], __ATOMIC_RELAXED,
                               __HIP_MEMORY_SCOPE_AGENT);
        v6 = __hip_atomic_load(&src[384], __ATOMIC_RELAXED,
                               __HIP_MEMORY_SCOPE_AGENT);
        v7 = __hip_atomic_load(&src[448], __ATOMIC_RELAXED,
                               __HIP_MEMORY_SCOPE_AGENT);
        v8 = __hip_atomic_load(&src[512], __ATOMIC_RELAXED,
                               __HIP_MEMORY_SCOPE_AGENT);
        v9 = __hip_atomic_load(&src[576], __ATOMIC_RELAXED,
                               __HIP_MEMORY_SCOPE_AGENT);
        va = __hip_atomic_load(&src[640], __ATOMIC_RELAXED,
                               __HIP_MEMORY_SCOPE_AGENT);
        vb = __hip_atomic_load(&src[704], __ATOMIC_RELAXED,
                               __HIP_MEMORY_SCOPE_AGENT);
        vc = __hip_atomic_load(&src[768], __ATOMIC_RELAXED,
                               __HIP_MEMORY_SCOPE_AGENT);
        vd = __hip_atomic_load(&src[832], __ATOMIC_RELAXED,
                               __HIP_MEMORY_SCOPE_AGENT);
        ve = __hip_atomic_load(&src[896], __ATOMIC_RELAXED,
                               __HIP_MEMORY_SCOPE_AGENT);
        vf = __hip_atomic_load(&src[960], __ATOMIC_RELAXED,
                               __HIP_MEMORY_SCOPE_AGENT);
        unsigned ok =
            ((unsigned)(v0 >> 32) == want) & ((unsigned)(v1 >> 32) == want) &
            ((unsigned)(v2 >> 32) == want) & ((unsigned)(v3 >> 32) == want) &
            ((unsigned)(v4 >> 32) == want) & ((unsigned)(v5 >> 32) == want) &
            ((unsigned)(v6 >> 32) == want) & ((unsigned)(v7 >> 32) == want) &
            ((unsigned)(v8 >> 32) == want) & ((unsigned)(v9 >> 32) == want) &
            ((unsigned)(va >> 32) == want) & ((unsigned)(vb >> 32) == want) &
            ((unsigned)(vc >> 32) == want) & ((unsigned)(vd >> 32) == want) &
            ((unsigned)(ve >> 32) == want) & ((unsigned)(vf >> 32) == want);
        if (ok) break;
      }
      if (lane < EDIM) lds_xbuf[p][lane] = xv;
      float* dst = lds_hf + p * HDIM + lane;
      dst[0] = __uint_as_float((unsigned)v0);
      dst[64] = __uint_as_float((unsigned)v1);
      dst[128] = __uint_as_float((unsigned)v2);
      dst[192] = __uint_as_float((unsigned)v3);
      dst[256] = __uint_as_float((unsigned)v4);
      dst[320] = __uint_as_float((unsigned)v5);
      dst[384] = __uint_as_float((unsigned)v6);
      dst[448] = __uint_as_float((unsigned)v7);
      dst[512] = __uint_as_float((unsigned)v8);
      dst[576] = __uint_as_float((unsigned)v9);
      dst[640] = __uint_as_float((unsigned)va);
      dst[704] = __uint_as_float((unsigned)vb);
      dst[768] = __uint_as_float((unsigned)vc);
      dst[832] = __uint_as_float((unsigned)vd);
      dst[896] = __uint_as_float((unsigned)ve);
      dst[960] = __uint_as_float((unsigned)vf);
      // drain this wave's LDS writes, then raise the flag (lane 0)
      asm volatile("s_waitcnt lgkmcnt(0)" ::: "memory");
      if (lane == 0) ((volatile int*)lds_rdy)[p] = t - 1;
    }
  } else {
    // =========================== COMPUTE WAVES ===========================
    const int myg = sl & 3;                    // gate computed by lanes 0..3
    const float gsc = (myg == 2) ? 2.f : 1.f;  // tanh via 2*sigmoid(2x)-1
    const float4* wl0 = lds_w4 + (size_t)(4 * lu + 0) * 256;  // lu<8 only
    const float4* wl1 = lds_w4 + (size_t)(4 * lu + 1) * 256;
    const float4* wl2 = lds_w4 + (size_t)(4 * lu + 2) * 256;
    const float4* wl3 = lds_w4 + (size_t)(4 * lu + 3) * 256;
    const float4* gg0 =
        (const float4*)(Whh + (size_t)(0 * HDIM + UPW * w + lu) * HDIM);
    const float4* gg1 =
        (const float4*)(Whh + (size_t)(1 * HDIM + UPW * w + lu) * HDIM);
    const float4* gg2 =
        (const float4*)(Whh + (size_t)(2 * HDIM + UPW * w + lu) * HDIM);
    const float4* gg3 =
        (const float4*)(Whh + (size_t)(3 * HDIM + UPW * w + lu) * HDIM);

    for (int t = 1; t <= TSTEPS; ++t) {
      const int p = (t - 1) & 3;
      // ---- CU-local spin on the poller's flag (no coherent traffic)
      volatile int* rp = (volatile int*)lds_rdy + p;
      while (*rp != t - 1) {
      }

      const float4* hb = lds_h4 + p * 256;
      float4 hv0 = hb[sl], hv1 = hb[sl + 32], hv2 = hb[sl + 64],
             hv3 = hb[sl + 96], hv4 = hb[sl + 128], hv5 = hb[sl + 160],
             hv6 = hb[sl + 192], hv7 = hb[sl + 224];

#define ROWDOT(dst, srcp)                                               \
  {                                                                     \
    float4 a = (srcp)[sl], b = (srcp)[sl + 32], c = (srcp)[sl + 64],    \
           d = (srcp)[sl + 96], e4 = (srcp)[sl + 128],                  \
           f4 = (srcp)[sl + 160], g4 = (srcp)[sl + 192],                \
           i4 = (srcp)[sl + 224];                                       \
    dst = (a.x * hv0.x + a.y * hv0.y + a.z * hv0.z + a.w * hv0.w) +     \
          (b.x * hv1.x + b.y * hv1.y + b.z * hv1.z + b.w * hv1.w) +     \
          (c.x * hv2.x + c.y * hv2.y + c.z * hv2.z + c.w * hv2.w) +     \
          (d.x * hv3.x + d.y * hv3.y + d.z * hv3.z + d.w * hv3.w) +     \
          (e4.x * hv4.x + e4.y * hv4.y + e4.z * hv4.z + e4.w * hv4.w) + \
          (f4.x * hv5.x + f4.y * hv5.y + f4.z * hv5.z + f4.w * hv5.w) + \
          (g4.x * hv6.x + g4.y * hv6.y + g4.z * hv6.z + g4.w * hv6.w) + \
          (i4.x * hv7.x + i4.y * hv7.y + i4.z * hv7.z + i4.w * hv7.w);  \
  }

      float acc0, acc1, acc2, acc3;
      if (lu < 8) {
        ROWDOT(acc0, wl0);
        ROWDOT(acc1, wl1);
        ROWDOT(acc2, wl2);
        ROWDOT(acc3, wl3);
      } else {
        ROWDOT(acc0, gg0);
        ROWDOT(acc1, gg1);
        ROWDOT(acc2, gg2);
        ROWDOT(acc3, gg3);
      }
#undef ROWDOT

      // ---- fold x-projection + biases (lane sl<4 pre-adds into acc_{sl})
      if (sl < 4) {
        int lrow = lu * 4 + sl;
        float xd = lds_bsum[lrow];
#pragma unroll
        for (int e = 0; e < EDIM; ++e) xd += lds_wih[lrow][e] * lds_xbuf[p][e];
        if (sl == 0) acc0 += xd;
        else if (sl == 1) acc1 += xd;
        else if (sl == 2) acc2 += xd;
        else acc3 += xd;
      }

      // ---- in-half reduce (xor masks 1..16 stay within the 32-lane half)
#pragma unroll
      for (int m = 1; m < 32; m <<= 1) {
        acc0 += __shfl_xor(acc0, m);
        acc1 += __shfl_xor(acc1, m);
        acc2 += __shfl_xor(acc2, m);
        acc3 += __shfl_xor(acc3, m);
      }

      // ---- activations: lanes 0..3 of each half, one exp chain each
      float pre = (myg == 0) ? acc0 : (myg == 1) ? acc1 : (myg == 2) ? acc2
                                                                     : acc3;
      float e = __expf(-gsc * pre);
      float y = 1.f / (1.f + e);
      float act = (myg == 2) ? 2.f * y - 1.f : y;

      int base = lane & 32;
      float ai = __shfl(act, base + 0);
      float af = __shfl(act, base + 1);
      float ag = __shfl(act, base + 2);
      float ao = __shfl(act, base + 3);
      if (sl == 0) {
        cst = af * cst + ai * ag;
        float e2 = __expf(-2.f * cst);
        float hn = ao * (2.f / (1.f + e2) - 1.f);
        ull pk = ((ull)(unsigned)t << 32) | (ull)__float_as_uint(hn);
        __hip_atomic_store(&hrec[(size_t)(t & 3) * HDIM + UPW * w + lu], pk,
                           __ATOMIC_RELAXED, __HIP_MEMORY_SCOPE_AGENT);
      }
    }
  }

  // ======================== TAIL (all 10 waves) ==========================
  __syncthreads();
  if (tid < 512) {
    const unsigned want = (unsigned)TSTEPS;  // parity (TSTEPS & 3) == 0
    ull v0 = __hip_atomic_load(&hrec[tid], __ATOMIC_RELAXED,
                               __HIP_MEMORY_SCOPE_AGENT);
    ull v1 = __hip_atomic_load(&hrec[tid + 512], __ATOMIC_RELAXED,
                               __HIP_MEMORY_SCOPE_AGENT);
    for (;;) {
      bool b0 = (unsigned)(v0 >> 32) == want;
      bool b1 = (unsigned)(v1 >> 32) == want;
      if (b0 && b1) break;
      if (!b0)
        v0 = __hip_atomic_load(&hrec[tid], __ATOMIC_RELAXED,
                               __HIP_MEMORY_SCOPE_AGENT);
      if (!b1)
        v1 = __hip_atomic_load(&hrec[tid + 512], __ATOMIC_RELAXED,
                               __HIP_MEMORY_SCOPE_AGENT);
    }
    lds_hf[tid] = __uint_as_float((unsigned)v0);
    lds_hf[tid + 512] = __uint_as_float((unsigned)v1);
  }
  __syncthreads();
  if (wave < 8) {
    int r1 = 8 * w + wave;  // one MLP row per wave, 512 rows over 64 WGs
    const float* w1p = W1 + (size_t)r1 * HDIM + lane * 16;
    float a0 = 0.f, a1 = 0.f;
#pragma unroll
    for (int i = 0; i < 16; i += 2) {
      a0 += w1p[i] * lds_hf[lane * 16 + i];
      a1 += w1p[i + 1] * lds_hf[lane * 16 + i + 1];
    }
    float acc1 = a0 + a1;
#pragma unroll
    for (int m = 1; m < 64; m <<= 1) acc1 += __shfl_xor(acc1, m);
    if (lane == 0) {
      float e2 = __expf(-2.f * (acc1 + b1[r1]));
      float u = 2.f / (1.f + e2) - 1.f;
      ull pk = (1ull << 32) | (ull)__float_as_uint(u);
      __hip_atomic_store(&urec[r1], pk, __ATOMIC_RELAXED,
                         __HIP_MEMORY_SCOPE_AGENT);
    }
  }

  // ---- tail step 2: out = W2 @ u + b2, WG 0 only -------------------------
  if (w == 0) {
    float p0 = 0.f, p1 = 0.f;
    if (tid < HLDIM) {
      ull uv = __hip_atomic_load(&urec[tid], __ATOMIC_RELAXED,
                                 __HIP_MEMORY_SCOPE_AGENT);
      while ((unsigned)(uv >> 32) != 1u)
        uv = __hip_atomic_load(&urec[tid], __ATOMIC_RELAXED,
                               __HIP_MEMORY_SCOPE_AGENT);
      float u = __uint_as_float((unsigned)uv);
      p0 = W2[tid] * u;
      p1 = W2[HLDIM + tid] * u;
    }
#pragma unroll
    for (int m = 1; m < 64; m <<= 1) {
      p0 += __shfl_xor(p0, m);
      p1 += __shfl_xor(p1, m);
    }
    if (lane == 0 && wave < 8) {
      lds_r0[wave] = p0;
      lds_r1[wave] = p1;
    }
    __syncthreads();
    if (tid == 0) {
      float o0 = b2[0], o1 = b2[1];
#pragma unroll
      for (int k = 0; k < 8; ++k) {
        o0 += lds_r0[k];
        o1 += lds_r1[k];
      }
      out[0] = o0;
      out[1] = o1;
    }
  }
}

extern "C" void kernel_launch(void* const* d_in, const int* in_sizes, int n_in,
                              void* d_out, int out_size, void* d_ws,
                              size_t ws_size, hipStream_t stream) {
  const float* x = (const float*)d_in[0];
  const float* h0 = (const float*)d_in[1];
  const float* c0 = (const float*)d_in[2];
  const float* Wih = (const float*)d_in[3];
  const float* Whh = (const float*)d_in[4];
  const float* bih = (const float*)d_in[5];
  const float* bhh = (const float*)d_in[6];
  const float* W1 = (const float*)d_in[7];
  const float* b1 = (const float*)d_in[8];
  const float* W2 = (const float*)d_in[9];
  const float* b2 = (const float*)d_in[10];
  float* out = (float*)d_out;

  ull* hrec = (ull*)d_ws;                                    // 4*1024*8 = 32 KB
  ull* urec = (ull*)((char*)d_ws + 4 * HDIM * sizeof(ull));  // 4 KB

  k_init<<<1, 1024, 0, stream>>>(h0, hrec, urec);
  k_main<<<NWG, NTHR, 0, stream>>>(x, c0, Wih, Whh, bih, bhh, W1, b1, W2, b2,
                                   out, hrec, urec);
}

// Round 11
// 67746.924 us; speedup vs baseline: 1.5075x; 1.5075x over previous
//
#include <hip/hip_runtime.h>
#include <cstdint>
#include <cstddef>

#define NWG 64
#define NTHR 512
#define UPW 16  // hidden units per WG
#define TSTEPS 16384
#define HDIM 1024
#define EDIM 13
#define HLDIM 512

typedef unsigned long long ull;

// ---------------------------------------------------------------------------
// Init kernel: re-arm the tagged h-record ring and u-record every call (d_ws
// is poisoned once with 0xAA and never re-poisoned between graph replays; a
// finished replay also leaves end-state tags behind, so every tag word must
// be rewritten each launch).
// hrec[parity][i] = { low32: f32 h value, high32: u32 step tag }, 4 parities.
// ---------------------------------------------------------------------------
__global__ void k_init(const float* __restrict__ h0, ull* __restrict__ hrec,
                       ull* __restrict__ urec) {
  int i = threadIdx.x;  // 1024 threads
  hrec[i] = (ull)__float_as_uint(h0[i]);  // {h0, tag=0}
  hrec[HDIM + i] = 0ull;
  hrec[2 * HDIM + i] = 0ull;
  hrec[3 * HDIM + i] = 0ull;
  if (i < HLDIM) urec[i] = 0ull;
}

// ---------------------------------------------------------------------------
// Persistent LSTM kernel. R8 skeleton + ONE change: DUAL-CHAIN INTERLEAVED
// POLL.
// Calibration (R1 vs R4): each protocol hop ~0.7us -> coherent-atomic RTT
// ~0.65us. Old poll: issue round -> vmcnt(0) -> check -> reissue = probe
// spacing ~RTT -> expected detect ~1.5*RTT. New poll: two independent probe
// chains in flight, checked alternately; each check waits only its own
// chain's counted vmcnt while the other is mid-flight -> sampling spacing
// ~RTT/2 -> detect ~1.25*RTT. (R10's wave-specialization regressed: poller
// storm + LDS-flag hop in series; reverted. R7's clustered poll failed
// because all 4 dup loads shared one vmcnt(0) wait - the dual chain fixes
// exactly that.)
// W residency: units 0..7 in 128 KB LDS (compiler-proof), units 8..15
// streamed from L2 (8 WGs/XCD x 128 KB = 1 MB working set, ~0.24us at the
// per-XCD L2 share - hidden under the sync chain).
// Cross-WG sync: self-validating {value, tag} 8-byte records, 4-deep global
// parity ring, relaxed agent-scope 64-bit atomics (single-copy, serviced at
// the device coherent point -> immune to non-coherent per-XCD L2s). One
// barrier per step.
// ---------------------------------------------------------------------------
__global__ __launch_bounds__(NTHR) void k_main(
    const float* __restrict__ x, const float* __restrict__ c0,
    const float* __restrict__ Wih, const float* __restrict__ Whh,
    const float* __restrict__ bih, const float* __restrict__ bhh,
    const float* __restrict__ W1, const float* __restrict__ b1,
    const float* __restrict__ W2, const float* __restrict__ b2,
    float* __restrict__ out, ull* hrec, ull* urec) {
  const int w = blockIdx.x;
  const int tid = threadIdx.x;
  const int wave = tid >> 6;     // 0..7
  const int lane = tid & 63;
  const int hi = lane >> 5;      // 0/1: which unit of the wave
  const int sl = lane & 31;      // sub-lane within the half
  const int lu = 2 * wave + hi;  // local unit 0..15

  __shared__ float4 lds_w4[32 * 256];  // units 0..7: row r=4*lu+g, 128 KB
  __shared__ float4 lds_h4[2 * 256];   // [parity][col4]
  __shared__ float lds_wih[64][17];    // row = 4*lu+g, stride 17
  __shared__ float lds_bsum[64];
  __shared__ float lds_r0[8], lds_r1[8];
  __shared__ float lds_xbuf[2][16];
  float* lds_hf = (float*)lds_h4;  // [2][1024] flat

  // ---- stage W for units 0..7 into LDS (one-time, coalesced) -------------
#pragma unroll
  for (int it = 0; it < 16; ++it) {
    int idx = it * NTHR + tid;  // 0..8191 float4s
    int r = idx >> 8;           // LDS row 0..31 (r = 4*lu + g)
    int c4 = idx & 255;
    int lu_ = r >> 2, g_ = r & 3;
    int grow = g_ * HDIM + UPW * w + lu_;
    lds_w4[r * 256 + c4] = ((const float4*)(Whh + (size_t)grow * HDIM))[c4];
  }
  if (tid < 64) {
    int lu_ = tid >> 2, g_ = tid & 3;
    int grow = g_ * HDIM + UPW * w + lu_;
#pragma unroll
    for (int e = 0; e < EDIM; ++e) lds_wih[tid][e] = Wih[grow * EDIM + e];
    lds_bsum[tid] = bih[grow] + bhh[grow];
  }
  // cell state: lane sl==0 of each half owns unit 16w+lu
  float cst = c0[UPW * w + lu];
  __syncthreads();

  const int myg = sl & 3;                    // gate computed by lanes 0..3
  const float gsc = (myg == 2) ? 2.f : 1.f;  // tanh via 2*sigmoid(2x)-1
  // W sources: LDS rows for lu<8, global rows (L2-resident) for lu>=8
  const float4* wl0 = lds_w4 + (size_t)(4 * lu + 0) * 256;  // lu<8 only
  const float4* wl1 = lds_w4 + (size_t)(4 * lu + 1) * 256;
  const float4* wl2 = lds_w4 + (size_t)(4 * lu + 2) * 256;
  const float4* wl3 = lds_w4 + (size_t)(4 * lu + 3) * 256;
  const float4* gg0 =
      (const float4*)(Whh + (size_t)(0 * HDIM + UPW * w + lu) * HDIM);
  const float4* gg1 =
      (const float4*)(Whh + (size_t)(1 * HDIM + UPW * w + lu) * HDIM);
  const float4* gg2 =
      (const float4*)(Whh + (size_t)(2 * HDIM + UPW * w + lu) * HDIM);
  const float4* gg3 =
      (const float4*)(Whh + (size_t)(3 * HDIM + UPW * w + lu) * HDIM);

  for (int t = 1; t <= TSTEPS; ++t) {
    const int lp = (t - 1) & 1;
    // ---- x_t prefetch: issue before the poll so latency hides there
    float xv = 0.f;
    if (tid < EDIM) xv = x[(size_t)(t - 1) * EDIM + tid];

    // ---- DUAL-CHAIN INTERLEAVED POLL of this thread's two records.
    // Two probe chains (xa/xb and ya/yb) alternate: while one chain's
    // result is being checked (counted vmcnt waits only for that chain),
    // the other chain's loads are already in flight -> sampling spacing
    // ~RTT/2 instead of ~RTT.
    const ull* rec0 = hrec + (size_t)((t - 1) & 3) * HDIM + tid;
    const ull* rec1 = rec0 + NTHR;
    const unsigned want = (unsigned)(t - 1);
    ull xa = __hip_atomic_load(rec0, __ATOMIC_RELAXED,
                               __HIP_MEMORY_SCOPE_AGENT);
    ull xb = __hip_atomic_load(rec1, __ATOMIC_RELAXED,
                               __HIP_MEMORY_SCOPE_AGENT);
    ull ya = __hip_atomic_load(rec0, __ATOMIC_RELAXED,
                               __HIP_MEMORY_SCOPE_AGENT);
    ull yb = __hip_atomic_load(rec1, __ATOMIC_RELAXED,
                               __HIP_MEMORY_SCOPE_AGENT);
    ull r0, r1;
    for (;;) {
      if (((unsigned)(xa >> 32) == want) & ((unsigned)(xb >> 32) == want)) {
        r0 = xa;
        r1 = xb;
        break;
      }
      xa = __hip_atomic_load(rec0, __ATOMIC_RELAXED,
                             __HIP_MEMORY_SCOPE_AGENT);
      xb = __hip_atomic_load(rec1, __ATOMIC_RELAXED,
                             __HIP_MEMORY_SCOPE_AGENT);
      if (((unsigned)(ya >> 32) == want) & ((unsigned)(yb >> 32) == want)) {
        r0 = ya;
        r1 = yb;
        break;
      }
      ya = __hip_atomic_load(rec0, __ATOMIC_RELAXED,
                             __HIP_MEMORY_SCOPE_AGENT);
      yb = __hip_atomic_load(rec1, __ATOMIC_RELAXED,
                             __HIP_MEMORY_SCOPE_AGENT);
    }
    lds_hf[lp * HDIM + tid] = __uint_as_float((unsigned)r0);
    lds_hf[lp * HDIM + tid + NTHR] = __uint_as_float((unsigned)r1);
    if (tid < EDIM) lds_xbuf[lp][tid] = xv;
    __syncthreads();

    // ---- h fragment: 8 contiguous float4s, reused across the 4 rows
    const float4* hb = lds_h4 + lp * 256;
    float4 hv0 = hb[sl], hv1 = hb[sl + 32], hv2 = hb[sl + 64],
           hv3 = hb[sl + 96], hv4 = hb[sl + 128], hv5 = hb[sl + 160],
           hv6 = hb[sl + 192], hv7 = hb[sl + 224];

#define ROWDOT(dst, srcp)                                               \
  {                                                                     \
    float4 a = (srcp)[sl], b = (srcp)[sl + 32], c = (srcp)[sl + 64],    \
           d = (srcp)[sl + 96], e4 = (srcp)[sl + 128],                  \
           f4 = (srcp)[sl + 160], g4 = (srcp)[sl + 192],                \
           i4 = (srcp)[sl + 224];                                       \
    dst = (a.x * hv0.x + a.y * hv0.y + a.z * hv0.z + a.w * hv0.w) +     \
          (b.x * hv1.x + b.y * hv1.y + b.z * hv1.z + b.w * hv1.w) +     \
          (c.x * hv2.x + c.y * hv2.y + c.z * hv2.z + c.w * hv2.w) +     \
          (d.x * hv3.x + d.y * hv3.y + d.z * hv3.z + d.w * hv3.w) +     \
          (e4.x * hv4.x + e4.y * hv4.y + e4.z * hv4.z + e4.w * hv4.w) + \
          (f4.x * hv5.x + f4.y * hv5.y + f4.z * hv5.z + f4.w * hv5.w) + \
          (g4.x * hv6.x + g4.y * hv6.y + g4.z * hv6.z + g4.w * hv6.w) + \
          (i4.x * hv7.x + i4.y * hv7.y + i4.z * hv7.z + i4.w * hv7.w);  \
  }

    float acc0, acc1, acc2, acc3;
    if (lu < 8) {
      ROWDOT(acc0, wl0);
      ROWDOT(acc1, wl1);
      ROWDOT(acc2, wl2);
      ROWDOT(acc3, wl3);
    } else {
      ROWDOT(acc0, gg0);
      ROWDOT(acc1, gg1);
      ROWDOT(acc2, gg2);
      ROWDOT(acc3, gg3);
    }
#undef ROWDOT

    // ---- fold x-projection + biases (lane sl<4 pre-adds into acc_{sl})
    if (sl < 4) {
      int lrow = lu * 4 + sl;
      float xd = lds_bsum[lrow];
#pragma unroll
      for (int e = 0; e < EDIM; ++e) xd += lds_wih[lrow][e] * lds_xbuf[lp][e];
      if (sl == 0) acc0 += xd;
      else if (sl == 1) acc1 += xd;
      else if (sl == 2) acc2 += xd;
      else acc3 += xd;
    }

    // ---- in-half reduce (xor masks 1..16 stay within the 32-lane half)
#pragma unroll
    for (int m = 1; m < 32; m <<= 1) {
      acc0 += __shfl_xor(acc0, m);
      acc1 += __shfl_xor(acc1, m);
      acc2 += __shfl_xor(acc2, m);
      acc3 += __shfl_xor(acc3, m);
    }

    // ---- activations: lanes 0..3 of each half, one exp chain each
    float pre = (myg == 0) ? acc0 : (myg == 1) ? acc1 : (myg == 2) ? acc2
                                                                   : acc3;
    float e = __expf(-gsc * pre);
    float y = 1.f / (1.f + e);
    float act = (myg == 2) ? 2.f * y - 1.f : y;

    int base = lane & 32;
    float ai = __shfl(act, base + 0);
    float af = __shfl(act, base + 1);
    float ag = __shfl(act, base + 2);
    float ao = __shfl(act, base + 3);
    if (sl == 0) {
      cst = af * cst + ai * ag;
      float e2 = __expf(-2.f * cst);
      float hn = ao * (2.f / (1.f + e2) - 1.f);
      ull pk = ((ull)(unsigned)t << 32) | (ull)__float_as_uint(hn);
      __hip_atomic_store(&hrec[(size_t)(t & 3) * HDIM + UPW * w + lu], pk,
                         __ATOMIC_RELAXED, __HIP_MEMORY_SCOPE_AGENT);
    }
    // no end-of-step barrier: publish is self-validating; LDS h parity is
    // reused 2 steps later, ordered by the intervening step's barrier.
  }

  // ---- tail step 1: u = tanh(W1 @ h_T + b1), 8 rows per WG ---------------
  {
    const unsigned want = (unsigned)TSTEPS;  // parity (TSTEPS & 3) == 0
    ull v0 = __hip_atomic_load(&hrec[tid], __ATOMIC_RELAXED,
                               __HIP_MEMORY_SCOPE_AGENT);
    ull v1 = __hip_atomic_load(&hrec[tid + NTHR], __ATOMIC_RELAXED,
                               __HIP_MEMORY_SCOPE_AGENT);
    for (;;) {
      bool b0 = (unsigned)(v0 >> 32) == want;
      bool b1 = (unsigned)(v1 >> 32) == want;
      if (b0 && b1) break;
      if (!b0)
        v0 = __hip_atomic_load(&hrec[tid], __ATOMIC_RELAXED,
                               __HIP_MEMORY_SCOPE_AGENT);
      if (!b1)
        v1 = __hip_atomic_load(&hrec[tid + NTHR], __ATOMIC_RELAXED,
                               __HIP_MEMORY_SCOPE_AGENT);
    }
    lds_hf[tid] = __uint_as_float((unsigned)v0);
    lds_hf[tid + NTHR] = __uint_as_float((unsigned)v1);
  }
  __syncthreads();
  {
    int r1 = 8 * w + wave;  // one MLP row per wave, 512 rows over 64 WGs
    const float* w1p = W1 + (size_t)r1 * HDIM + lane * 16;
    float a0 = 0.f, a1 = 0.f;
#pragma unroll
    for (int i = 0; i < 16; i += 2) {
      a0 += w1p[i] * lds_hf[lane * 16 + i];
      a1 += w1p[i + 1] * lds_hf[lane * 16 + i + 1];
    }
    float acc1 = a0 + a1;
#pragma unroll
    for (int m = 1; m < 64; m <<= 1) acc1 += __shfl_xor(acc1, m);
    if (lane == 0) {
      float e2 = __expf(-2.f * (acc1 + b1[r1]));
      float u = 2.f / (1.f + e2) - 1.f;
      ull pk = (1ull << 32) | (ull)__float_as_uint(u);
      __hip_atomic_store(&urec[r1], pk, __ATOMIC_RELAXED,
                         __HIP_MEMORY_SCOPE_AGENT);
    }
  }

  // ---- tail step 2: out = W2 @ u + b2, WG 0 only -------------------------
  if (w == 0) {
    ull uv = __hip_atomic_load(&urec[tid], __ATOMIC_RELAXED,
                               __HIP_MEMORY_SCOPE_AGENT);
    while ((unsigned)(uv >> 32) != 1u)
      uv = __hip_atomic_load(&urec[tid], __ATOMIC_RELAXED,
                             __HIP_MEMORY_SCOPE_AGENT);
    float u = __uint_as_float((unsigned)uv);
    float p0 = W2[tid] * u;
    float p1 = W2[HLDIM + tid] * u;
#pragma unroll
    for (int m = 1; m < 64; m <<= 1) {
      p0 += __shfl_xor(p0, m);
      p1 += __shfl_xor(p1, m);
    }
    if (lane == 0) {
      lds_r0[wave] = p0;
      lds_r1[wave] = p1;
    }
    __syncthreads();
    if (tid == 0) {
      float o0 = b2[0], o1 = b2[1];
#pragma unroll
      for (int k = 0; k < 8; ++k) {
        o0 += lds_r0[k];
        o1 += lds_r1[k];
      }
      out[0] = o0;
      out[1] = o1;
    }
  }
}

extern "C" void kernel_launch(void* const* d_in, const int* in_sizes, int n_in,
                              void* d_out, int out_size, void* d_ws,
                              size_t ws_size, hipStream_t stream) {
  const float* x = (const float*)d_in[0];
  const float* h0 = (const float*)d_in[1];
  const float* c0 = (const float*)d_in[2];
  const float* Wih = (const float*)d_in[3];
  const float* Whh = (const float*)d_in[4];
  const float* bih = (const float*)d_in[5];
  const float* bhh = (const float*)d_in[6];
  const float* W1 = (const float*)d_in[7];
  const float* b1 = (const float*)d_in[8];
  const float* W2 = (const float*)d_in[9];
  const float* b2 = (const float*)d_in[10];
  float* out = (float*)d_out;

  ull* hrec = (ull*)d_ws;                                    // 4*1024*8 = 32 KB
  ull* urec = (ull*)((char*)d_ws + 4 * HDIM * sizeof(ull));  // 4 KB

  k_init<<<1, 1024, 0, stream>>>(h0, hrec, urec);
  k_main<<<NWG, NTHR, 0, stream>>>(x, c0, Wih, Whh, bih, bhh, W1, b1, W2, b2,
                                   out, hrec, urec);
}

// Round 13
// 48720.532 us; speedup vs baseline: 2.0962x; 1.3905x over previous
//
#include <hip/hip_runtime.h>
#include <cstdint>
#include <cstddef>

#define NWG 64
#define NTHR 512
#define TSTEPS 16384
#define HDIM 1024
#define EDIM 13
#define HLDIM 512

typedef unsigned long long ull;

// ---------------------------------------------------------------------------
// Init kernel: re-arm the tagged h-record ring and u-record every call (d_ws
// is poisoned once with 0xAA and never re-poisoned between graph replays; a
// finished replay also leaves end-state tags behind, so every tag word must
// be rewritten each launch).
// hrec[parity][i] = { low32: f32 h value, high32: u32 step tag }, 4 parities.
// ---------------------------------------------------------------------------
__global__ void k_init(const float* __restrict__ h0, ull* __restrict__ hrec,
                       ull* __restrict__ urec) {
  int i = threadIdx.x;
  hrec[i] = (ull)__float_as_uint(h0[i]);  // {h0, tag=0}
  hrec[HDIM + i] = 0ull;
  hrec[2 * HDIM + i] = 0ull;
  hrec[3 * HDIM + i] = 0ull;
  if (i < HLDIM) urec[i] = 0ull;
}

// ---------------------------------------------------------------------------
// Persistent LSTM kernel — ROUND-4 KERNEL VERBATIM (best measured: 49.3 ms)
// + ONE change: a ~90 KB LDS pad. (Resubmission of round 12 — the container
// died before that round was ever pushed/measured.)
// Why: R4's W (128 floats/thread, asm-pinned) spilled to scratch
// (VGPR_Count=92). That turned out to be half-good: scratch reloads are
// private, so the compiler hoists them ABOVE the poll/barrier and the W
// fetch pipelines during the sync wait (this is why R4 beats every LDS-W
// variant, where LDS reads can't cross the barrier). The remaining loss is
// scratch round-trip traffic. Hypothesis: the spill happened because with
// 13 KB LDS the allocator assumed multi-WG occupancy and a small VGPR
// budget; R8 showed that ~105-144 KB static LDS collapses the assumption to
// 1 WG/CU -> 2 waves/SIMD -> 256-VGPR budget (it allocated without
// pressure). The pad applies that budget here WITHOUT touching anything
// else. If the allocator now keeps W resident: no scratch traffic, W truly
// in regs -> ~1.9-2.3 us/step. If it still spills: identical R4 behavior
// (~49 ms), and that establishes the protocol floor for this decomposition.
// Cross-WG sync: self-validating {value, tag} 8-byte records in a 4-deep
// parity ring, relaxed agent-scope 64-bit atomics (single-copy, serviced at
// the device coherent point -> immune to non-coherent per-XCD L2s). One
// coherent round trip + one __syncthreads per step.
// ---------------------------------------------------------------------------
__global__ __launch_bounds__(NTHR)
__attribute__((amdgpu_waves_per_eu(2, 2))) void k_main(
    const float* __restrict__ x, const float* __restrict__ c0,
    const float* __restrict__ Wih, const float* __restrict__ Whh,
    const float* __restrict__ bih, const float* __restrict__ bhh,
    const float* __restrict__ W1, const float* __restrict__ b1,
    const float* __restrict__ W2, const float* __restrict__ b2,
    float* __restrict__ out, ull* hrec, ull* urec, int never) {
  const int w = blockIdx.x;
  const int tid = threadIdx.x;
  const int sub = tid & 7;    // col-chunk index within row (8 x 128 cols)
  const int row = tid >> 3;   // local gate row 0..63
  const int wave = tid >> 6;  // 0..7
  const int lane = tid & 63;
  const int g = row & 3;      // 0=i 1=f 2=g 3=o
  const int lu = row >> 2;    // local unit 0..15
  const int grow = g * HDIM + w * 16 + lu;  // global gate row (gate-major)

  __shared__ float4 lds_h4[2][HDIM / 4];  // double-buffered by step parity
  __shared__ float lds_x[2][16];
  __shared__ float lds_wih[64][17];  // stride 17: conflict-free owner reads
  __shared__ float lds_bsum[64];
  __shared__ float lds_r0[8], lds_r1[8];
  // Occupancy-budget clamp: ~90 KB pad -> 2nd WG can never co-reside ->
  // register allocator budgets 256 VGPRs/thread (2 waves/SIMD).
  __shared__ float lds_pad[23040];  // 90 KB
  float* lds_hf = (float*)lds_h4;   // [2][1024] flat
  if (never) ((volatile float*)lds_pad)[0] = 1.f;  // keep pad allocated

  // ---- load this thread's W_hh chunk, rotated so the wave's 8 distinct LDS
  // b128 addresses at compute time cover all 32 banks (conflict-free, 8-way
  // same-address broadcast within each sub group).
  float4 wreg[32];
  const float4* wrow = (const float4*)(Whh + (size_t)grow * HDIM) + sub * 32;
#pragma unroll
  for (int i = 0; i < 32; ++i) wreg[i] = wrow[(i + sub) & 31];
  // Pin in VGPRs: the asm claims to rewrite each value, so the compiler can
  // neither rematerialize the global loads nor fold them into the loop.
#pragma unroll
  for (int i = 0; i < 32; ++i)
    asm volatile("" : "+v"(wreg[i].x), "+v"(wreg[i].y), "+v"(wreg[i].z),
                     "+v"(wreg[i].w));

  if (tid < 64) {
    int g2 = tid & 3, lu2 = tid >> 2;
    int gr2 = g2 * HDIM + w * 16 + lu2;
#pragma unroll
    for (int e = 0; e < EDIM; ++e) lds_wih[tid][e] = Wih[gr2 * EDIM + e];
    lds_bsum[tid] = bih[gr2] + bhh[gr2];
  }
  // cell state: lanes 0 and 32 of each wave own units 2*wave and 2*wave+1
  float cst = c0[w * 16 + 2 * wave + (lane >> 5)];
  __syncthreads();

  const float gsc = (g == 2) ? 2.f : 1.f;  // tanh via 2*sigmoid(2x)-1

  for (int t = 1; t <= TSTEPS; ++t) {
    const int lp = (t - 1) & 1;  // LDS parity (2-deep, barrier-separated)
    // ---- x_t prefetch: issue before the poll so its latency hides there
    float xv = 0.f;
    if (tid < EDIM) xv = x[(size_t)(t - 1) * EDIM + tid];

    // ---- poll this thread's two {h, tag} chunks of h_{t-1}; the poll load
    // IS the data load (one MALL round trip). 4-deep ring: overwrite of a
    // tag-t chunk (by tag t+4) needs three cross-WG dependence chains of
    // separation -> overwrite-before-read unreachable.
    const ull* src = hrec + (size_t)((t - 1) & 3) * HDIM;
    const unsigned want = (unsigned)(t - 1);
    ull v0 = __hip_atomic_load(&src[tid], __ATOMIC_RELAXED,
                               __HIP_MEMORY_SCOPE_AGENT);
    ull v1 = __hip_atomic_load(&src[tid + NTHR], __ATOMIC_RELAXED,
                               __HIP_MEMORY_SCOPE_AGENT);
    for (;;) {
      bool b0 = (unsigned)(v0 >> 32) == want;
      bool b1 = (unsigned)(v1 >> 32) == want;
      if (b0 && b1) break;
      if (!b0)
        v0 = __hip_atomic_load(&src[tid], __ATOMIC_RELAXED,
                               __HIP_MEMORY_SCOPE_AGENT);
      if (!b1)
        v1 = __hip_atomic_load(&src[tid + NTHR], __ATOMIC_RELAXED,
                               __HIP_MEMORY_SCOPE_AGENT);
    }
    lds_hf[lp * HDIM + tid] = __uint_as_float((unsigned)v0);
    lds_hf[lp * HDIM + tid + NTHR] = __uint_as_float((unsigned)v1);
    if (tid < EDIM) lds_x[lp][tid] = xv;
    __syncthreads();

    // ---- gate pre-activation: x-projection folded into the same reduction
    float acc = lds_wih[row][sub] * lds_x[lp][sub];
    if (sub < EDIM - 8) acc += lds_wih[row][sub + 8] * lds_x[lp][sub + 8];
    if (sub == 0) acc += lds_bsum[row];
#pragma unroll
    for (int i = 0; i < 32; ++i) {
      float4 hv = lds_h4[lp][sub * 32 + ((i + sub) & 31)];
      float4 wv = wreg[i];
      acc += wv.x * hv.x;
      acc += wv.y * hv.y;
      acc += wv.z * hv.z;
      acc += wv.w * hv.w;
    }
    acc += __shfl_xor(acc, 1);
    acc += __shfl_xor(acc, 2);
    acc += __shfl_xor(acc, 4);

    // ---- activations computed in parallel on all lanes (one exp chain)
    float e = __expf(-gsc * acc);
    float y = 1.f / (1.f + e);
    float act = (g == 2) ? 2.f * y - 1.f : y;

    int base = lane & 32;
    float ai = __shfl(act, base + 0);
    float af = __shfl(act, base + 8);
    float ag = __shfl(act, base + 16);
    float ao = __shfl(act, base + 24);
    if ((lane & 31) == 0) {
      cst = af * cst + ai * ag;
      float e2 = __expf(-2.f * cst);
      float hn = ao * (2.f / (1.f + e2) - 1.f);
      ull pk = ((ull)(unsigned)t << 32) | (ull)__float_as_uint(hn);
      __hip_atomic_store(&hrec[(size_t)(t & 3) * HDIM + w * 16 + 2 * wave +
                               (lane >> 5)],
                         pk, __ATOMIC_RELAXED, __HIP_MEMORY_SCOPE_AGENT);
    }
    // no end-of-step barrier: publish is self-validating; LDS buffer reuse is
    // two steps away and ordered by the intervening step's __syncthreads.
  }

  // ---- tail step 1: u = tanh(W1 @ h_T + b1), 8 rows per WG --------------
  {
    // h_T: tag TSTEPS lives in ring parity (TSTEPS & 3) == 0
    const unsigned want = (unsigned)TSTEPS;
    ull v0 = __hip_atomic_load(&hrec[tid], __ATOMIC_RELAXED,
                               __HIP_MEMORY_SCOPE_AGENT);
    ull v1 = __hip_atomic_load(&hrec[tid + NTHR], __ATOMIC_RELAXED,
                               __HIP_MEMORY_SCOPE_AGENT);
    for (;;) {
      bool b0 = (unsigned)(v0 >> 32) == want;
      bool b1 = (unsigned)(v1 >> 32) == want;
      if (b0 && b1) break;
      if (!b0)
        v0 = __hip_atomic_load(&hrec[tid], __ATOMIC_RELAXED,
                               __HIP_MEMORY_SCOPE_AGENT);
      if (!b1)
        v1 = __hip_atomic_load(&hrec[tid + NTHR], __ATOMIC_RELAXED,
                               __HIP_MEMORY_SCOPE_AGENT);
    }
    lds_hf[tid] = __uint_as_float((unsigned)v0);
    lds_hf[tid + NTHR] = __uint_as_float((unsigned)v1);
  }
  __syncthreads();
  {
    int r1 = 8 * w + wave;  // one MLP row per wave
    const float* w1p = W1 + (size_t)r1 * HDIM + lane * 16;
    float acc1 = 0.f;
#pragma unroll
    for (int i = 0; i < 16; ++i) acc1 += w1p[i] * lds_hf[lane * 16 + i];
#pragma unroll
    for (int m = 1; m < 64; m <<= 1) acc1 += __shfl_xor(acc1, m);
    if (lane == 0) {
      float e2 = __expf(-2.f * (acc1 + b1[r1]));
      float u = 2.f / (1.f + e2) - 1.f;
      ull pk = (1ull << 32) | (ull)__float_as_uint(u);
      __hip_atomic_store(&urec[r1], pk, __ATOMIC_RELAXED,
                         __HIP_MEMORY_SCOPE_AGENT);
    }
  }

  // ---- tail step 2: out = W2 @ u + b2, WG 0 only -------------------------
  if (w == 0) {
    ull uv = __hip_atomic_load(&urec[tid], __ATOMIC_RELAXED,
                               __HIP_MEMORY_SCOPE_AGENT);
    while ((unsigned)(uv >> 32) != 1u)
      uv = __hip_atomic_load(&urec[tid], __ATOMIC_RELAXED,
                             __HIP_MEMORY_SCOPE_AGENT);
    float u = __uint_as_float((unsigned)uv);
    float p0 = W2[tid] * u;
    float p1 = W2[HLDIM + tid] * u;
#pragma unroll
    for (int m = 1; m < 64; m <<= 1) {
      p0 += __shfl_xor(p0, m);
      p1 += __shfl_xor(p1, m);
    }
    if (lane == 0) {
      lds_r0[wave] = p0;
      lds_r1[wave] = p1;
    }
    __syncthreads();
    if (tid == 0) {
      float o0 = b2[0], o1 = b2[1];
#pragma unroll
      for (int k = 0; k < 8; ++k) {
        o0 += lds_r0[k];
        o1 += lds_r1[k];
      }
      out[0] = o0;
      out[1] = o1;
    }
  }
}

extern "C" void kernel_launch(void* const* d_in, const int* in_sizes, int n_in,
                              void* d_out, int out_size, void* d_ws,
                              size_t ws_size, hipStream_t stream) {
  const float* x = (const float*)d_in[0];
  const float* h0 = (const float*)d_in[1];
  const float* c0 = (const float*)d_in[2];
  const float* Wih = (const float*)d_in[3];
  const float* Whh = (const float*)d_in[4];
  const float* bih = (const float*)d_in[5];
  const float* bhh = (const float*)d_in[6];
  const float* W1 = (const float*)d_in[7];
  const float* b1 = (const float*)d_in[8];
  const float* W2 = (const float*)d_in[9];
  const float* b2 = (const float*)d_in[10];
  float* out = (float*)d_out;

  ull* hrec = (ull*)d_ws;                                    // 4*1024*8 = 32 KB
  ull* urec = (ull*)((char*)d_ws + 4 * HDIM * sizeof(ull));  // 4 KB

  k_init<<<1, 1024, 0, stream>>>(h0, hrec, urec);
  k_main<<<NWG, NTHR, 0, stream>>>(x, c0, Wih, Whh, bih, bhh, W1, b1, W2, b2,
                                   out, hrec, urec, 0);
}